// Round 9
// baseline (1142.755 us; speedup 1.0000x reference)
//
#include <hip/hip_runtime.h>

#define NN 50000
#define EE 600000
#define DD 128
#define DD2 256
#define LL 5
#define BN_EPS 1e-5f

typedef __attribute__((ext_vector_type(8))) _Float16 half8;
typedef __attribute__((ext_vector_type(4))) float f32x4;

__device__ inline unsigned short f2h_bits(float f) {
    _Float16 h = (_Float16)f;  // RTNE
    return __builtin_bit_cast(unsigned short, h);
}
__device__ inline float h2f(unsigned short u) {
    return (float)__builtin_bit_cast(_Float16, u);
}
__device__ inline half8 bnrelu8(half8 v, half8 s, half8 t) {
    half8 r = v * s + t;
#pragma unroll
    for (int k = 0; k < 8; k++) r[k] = (r[k] > (_Float16)0) ? r[k] : (_Float16)0;
    return r;
}

// ---------------- CSR build ----------------

__global__ void hist_kernel(const int* __restrict__ dst, int* __restrict__ counts) {
    int e = blockIdx.x * blockDim.x + threadIdx.x;
    if (e < EE) atomicAdd(&counts[dst[e]], 1);
}

__global__ void scan1_kernel(const int* __restrict__ counts, int* __restrict__ row_ptr,
                             int* __restrict__ blksum) {
    __shared__ int tmp[256];
    int i = blockIdx.x * 256 + threadIdx.x;
    int v = (i < NN) ? counts[i] : 0;
    tmp[threadIdx.x] = v;
    __syncthreads();
    for (int off = 1; off < 256; off <<= 1) {
        int x = 0;
        if (threadIdx.x >= off) x = tmp[threadIdx.x - off];
        __syncthreads();
        if (threadIdx.x >= off) tmp[threadIdx.x] += x;
        __syncthreads();
    }
    if (i < NN) row_ptr[i] = tmp[threadIdx.x] - v;
    if (threadIdx.x == 255) blksum[blockIdx.x] = tmp[255];
}

__global__ void scan2_kernel(int* __restrict__ blksum, int nblocks) {
    __shared__ int tmp[256];
    int v = (threadIdx.x < nblocks) ? blksum[threadIdx.x] : 0;
    tmp[threadIdx.x] = v;
    __syncthreads();
    for (int off = 1; off < 256; off <<= 1) {
        int x = 0;
        if (threadIdx.x >= off) x = tmp[threadIdx.x - off];
        __syncthreads();
        if (threadIdx.x >= off) tmp[threadIdx.x] += x;
        __syncthreads();
    }
    blksum[threadIdx.x] = tmp[threadIdx.x] - v;
}

__global__ void scan3_kernel(int* __restrict__ row_ptr, const int* __restrict__ blksum) {
    int i = blockIdx.x * 256 + threadIdx.x;
    if (i < NN) row_ptr[i] += blksum[blockIdx.x];
    if (i == 0) row_ptr[NN] = EE;
}

// scatter + pack edge data: edata[p] = {src, cid | w_fp16<<16}
__global__ void scatter_kernel(const int* __restrict__ dst, const int* __restrict__ src,
                               const int* __restrict__ edge_attr, const float* __restrict__ ew,
                               const int* __restrict__ row_ptr, int* __restrict__ cursor,
                               uint2* __restrict__ edata) {
    int e = blockIdx.x * blockDim.x + threadIdx.x;
    if (e < EE) {
        int d = dst[e];
        int p = row_ptr[d] + atomicAdd(&cursor[d], 1);
        int cid = edge_attr[3 * e + 0] + 8 * edge_attr[3 * e + 1] + 64 * edge_attr[3 * e + 2];
        uint2 v;
        v.x = (unsigned)src[e];
        v.y = (unsigned)cid | ((unsigned)f2h_bits(ew[e]) << 16);
        edata[p] = v;
    }
}

// ---------------- degree sort (counting sort, 128 bins) ----------------

__global__ void deg_hist_kernel(const int* __restrict__ row_ptr, int* __restrict__ dbin) {
    int n = blockIdx.x * 256 + threadIdx.x;
    if (n < NN) {
        int d = row_ptr[n + 1] - row_ptr[n];
        if (d > 127) d = 127;
        atomicAdd(&dbin[d], 1);
    }
}

__global__ void deg_scan_kernel(int* __restrict__ dbin) {
    __shared__ int t[128];
    int i = threadIdx.x;  // 128 threads
    int v = dbin[i];
    t[i] = v;
    __syncthreads();
    for (int off = 1; off < 128; off <<= 1) {
        int x = 0;
        if (i >= off) x = t[i - off];
        __syncthreads();
        if (i >= off) t[i] += x;
        __syncthreads();
    }
    dbin[i] = t[i] - v;  // exclusive
}

__global__ void deg_scatter_kernel(const int* __restrict__ row_ptr, int* __restrict__ dcur,
                                   int* __restrict__ order) {
    int n = blockIdx.x * 256 + threadIdx.x;
    if (n < NN) {
        int d = row_ptr[n + 1] - row_ptr[n];
        if (d > 127) d = 127;
        int pos = atomicAdd(&dcur[d], 1);
        order[pos] = n;
    }
}

// ---------------- table prep: W1t, W2t (fp16, [M][K]) + combined bond table (fp16) ------------

__global__ void prep_tables_kernel(const float* __restrict__ W1, const float* __restrict__ W2,
                                   const float* __restrict__ bond_emb,
                                   unsigned short* __restrict__ W1t,
                                   unsigned short* __restrict__ W2t,
                                   unsigned short* __restrict__ bsum) {
    const int NW = LL * DD * DD2;  // 163840
    int idx = blockIdx.x * 256 + threadIdx.x;
    if (idx < NW) {
        int l = idx / (DD * DD2);
        int rem = idx - l * DD * DD2;
        int k = rem / DD2, m = rem - k * DD2;  // W1: [L][128][256]
        W1t[(size_t)l * DD * DD2 + (size_t)m * DD + k] = f2h_bits(W1[idx]);
    } else if (idx < 2 * NW) {
        int j = idx - NW;
        int l = j / (DD * DD2);
        int rem = j - l * DD * DD2;
        int k = rem / DD, m = rem - k * DD;  // W2: [L][256][128]
        W2t[(size_t)l * DD * DD2 + (size_t)m * DD2 + k] = f2h_bits(W2[j]);
    } else if (idx < 2 * NW + LL * 512 * DD) {
        int j = idx - 2 * NW;
        int l = j >> 16;  // 512*128
        int rem = j & 65535;
        int cid = rem >> 7, d = rem & 127;
        int a0 = cid & 7, a1 = (cid >> 3) & 7, a2 = cid >> 6;
        const float* base = bond_emb + (size_t)l * 3 * 8 * DD;
        bsum[j] = f2h_bits(base[a0 * DD + d] + base[(8 + a1) * DD + d] + base[(16 + a2) * DD + d]);
    }
}

// ---------------- node init (fp16 h0) ----------------

__global__ void init_h_kernel(const int* __restrict__ x, const float* __restrict__ atom_emb,
                              unsigned short* __restrict__ h) {
    int n = blockIdx.x * 8 + (threadIdx.x >> 5);
    int lane = threadIdx.x & 31;
    float a0 = 0.f, a1 = 0.f, a2 = 0.f, a3 = 0.f;
#pragma unroll
    for (int f = 0; f < 9; f++) {
        int idx = x[n * 9 + f];
        const float4 v = *(const float4*)(atom_emb + ((size_t)(f * 64 + idx) * DD) + lane * 4);
        a0 += v.x; a1 += v.y; a2 += v.z; a3 += v.w;
    }
    ushort4 o;
    o.x = f2h_bits(a0); o.y = f2h_bits(a1); o.z = f2h_bits(a2); o.w = f2h_bits(a3);
    *(ushort4*)(h + (size_t)n * DD + lane * 4) = o;
}

// ---------------- FUSED: edge aggregate (+BN2+relu of prev layer) + GEMM1 + stats1 -----------
// Block = 16 nodes (degree-sorted via order[]). Phase 1: gather 16x128 A-tile into LDS.
// Phase 2: A-tile @ W1t (K=128 -> M=256) via MFMA, +bias, write z1, atomic col stats.

template <bool FUSE>
__global__ __launch_bounds__(256, 4) void agg_mlp1_kernel(
    const unsigned short* __restrict__ hsrc, const float* __restrict__ stats,
    const float* __restrict__ g, const float* __restrict__ bb,
    const int* __restrict__ row_ptr, const uint2* __restrict__ edata,
    const unsigned short* __restrict__ bsum_l, const float* __restrict__ eps_ptr,
    const int* __restrict__ order, const unsigned short* __restrict__ W1t,
    const float* __restrict__ bias1, unsigned short* __restrict__ z1,
    float* __restrict__ stats1) {
    __shared__ _Float16 As[16 * DD];
    __shared__ int rowids[16];
    int tid = threadIdx.x;
    int lane16 = tid & 15;
    int s = tid >> 4;  // 0..15 sub-node
    int c0 = lane16 * 8;
    int n = order[blockIdx.x * 16 + s];
    if (lane16 == 0) rowids[s] = n;

    float bs[8], bt[8];
    if (FUSE) {
#pragma unroll
        for (int k = 0; k < 8; k++) {
            int c = c0 + k;
            float mean = stats[c] * (1.f / NN);
            float var = stats[DD + c] * (1.f / NN) - mean * mean;
            float sc = g[c] * rsqrtf(var + BN_EPS);
            bs[k] = sc;
            bt[k] = bb[c] - mean * sc;
        }
    }

    float acc[8] = {0.f, 0.f, 0.f, 0.f, 0.f, 0.f, 0.f, 0.f};

    auto accum = [&](uint2 ed, uint4 hz, uint4 bz) {
        float w = h2f((unsigned short)(ed.y >> 16));
        unsigned int hw[4] = {hz.x, hz.y, hz.z, hz.w};
        unsigned int bw[4] = {bz.x, bz.y, bz.z, bz.w};
#pragma unroll
        for (int k = 0; k < 4; k++) {
            float hv0 = h2f((unsigned short)(hw[k] & 0xffff));
            float hv1 = h2f((unsigned short)(hw[k] >> 16));
            if (FUSE) {
                hv0 = fmaxf(hv0 * bs[2 * k] + bt[2 * k], 0.f);
                hv1 = fmaxf(hv1 * bs[2 * k + 1] + bt[2 * k + 1], 0.f);
            }
            float m0 = fmaxf(hv0 + h2f((unsigned short)(bw[k] & 0xffff)), 0.f);
            float m1 = fmaxf(hv1 + h2f((unsigned short)(bw[k] >> 16)), 0.f);
            acc[2 * k] += m0 * w;
            acc[2 * k + 1] += m1 * w;
        }
    };

    int beg = row_ptr[n], end = row_ptr[n + 1];
    int i = beg;
    for (; i + 4 <= end; i += 4) {
        uint2 e0 = edata[i], e1 = edata[i + 1], e2 = edata[i + 2], e3 = edata[i + 3];
        uint4 h0 = *(const uint4*)(hsrc + (size_t)e0.x * DD + c0);
        uint4 b0 = *(const uint4*)(bsum_l + (size_t)(e0.y & 0xffff) * DD + c0);
        uint4 h1 = *(const uint4*)(hsrc + (size_t)e1.x * DD + c0);
        uint4 b1 = *(const uint4*)(bsum_l + (size_t)(e1.y & 0xffff) * DD + c0);
        uint4 h2 = *(const uint4*)(hsrc + (size_t)e2.x * DD + c0);
        uint4 b2 = *(const uint4*)(bsum_l + (size_t)(e2.y & 0xffff) * DD + c0);
        uint4 h3 = *(const uint4*)(hsrc + (size_t)e3.x * DD + c0);
        uint4 b3 = *(const uint4*)(bsum_l + (size_t)(e3.y & 0xffff) * DD + c0);
        accum(e0, h0, b0);
        accum(e1, h1, b1);
        accum(e2, h2, b2);
        accum(e3, h3, b3);
    }
    for (; i < end; i++) {
        uint2 e0 = edata[i];
        uint4 h0 = *(const uint4*)(hsrc + (size_t)e0.x * DD + c0);
        uint4 b0 = *(const uint4*)(bsum_l + (size_t)(e0.y & 0xffff) * DD + c0);
        accum(e0, h0, b0);
    }

    // self term + pack to LDS
    {
        float eps1 = 1.f + eps_ptr[0];
        uint4 hz = *(const uint4*)(hsrc + (size_t)n * DD + c0);
        unsigned int hw[4] = {hz.x, hz.y, hz.z, hz.w};
        uint4 packed;
        unsigned int* pp = (unsigned int*)&packed;
#pragma unroll
        for (int k = 0; k < 4; k++) {
            float hv0 = h2f((unsigned short)(hw[k] & 0xffff));
            float hv1 = h2f((unsigned short)(hw[k] >> 16));
            if (FUSE) {
                hv0 = fmaxf(hv0 * bs[2 * k] + bt[2 * k], 0.f);
                hv1 = fmaxf(hv1 * bs[2 * k + 1] + bt[2 * k + 1], 0.f);
            }
            float v0 = eps1 * hv0 + acc[2 * k];
            float v1 = eps1 * hv1 + acc[2 * k + 1];
            pp[k] = (unsigned int)f2h_bits(v0) | ((unsigned int)f2h_bits(v1) << 16);
        }
        *(uint4*)(As + s * DD + c0) = packed;
    }
    __syncthreads();

    // ---- phase 2: 16x128 @ 128x256 ----
    int wave = tid >> 6;
    int lane = tid & 63;
    int lr = lane & 15;
    int q = lane >> 4;
    int colbase = wave * 64;

    half8 bfr[4][4];  // [j][ks]
#pragma unroll
    for (int j = 0; j < 4; j++) {
        const unsigned short* bp = W1t + (size_t)(colbase + j * 16 + lr) * DD + q * 8;
#pragma unroll
        for (int ks = 0; ks < 4; ks++)
            bfr[j][ks] = __builtin_bit_cast(half8, *(const int4*)(bp + ks * 32));
    }
    half8 afr[4];
#pragma unroll
    for (int ks = 0; ks < 4; ks++)
        afr[ks] = *(const half8*)(As + lr * DD + ks * 32 + q * 8);

    f32x4 acc4[4];
#pragma unroll
    for (int j = 0; j < 4; j++) acc4[j] = (f32x4){0.f, 0.f, 0.f, 0.f};
#pragma unroll
    for (int ks = 0; ks < 4; ks++)
#pragma unroll
        for (int j = 0; j < 4; j++)
            acc4[j] = __builtin_amdgcn_mfma_f32_16x16x32_f16(afr[ks], bfr[j][ks], acc4[j], 0, 0, 0);

#pragma unroll
    for (int j = 0; j < 4; j++) {
        int c = colbase + j * 16 + lr;
        float bi = bias1[c];
        float sm = 0.f, sq = 0.f;
#pragma unroll
        for (int r = 0; r < 4; r++) {
            int rl = q * 4 + r;
            float v = acc4[j][r] + bi;
            z1[(size_t)rowids[rl] * DD2 + c] = f2h_bits(v);
            sm += v;
            sq += v * v;
        }
        sm += __shfl_xor(sm, 16);
        sm += __shfl_xor(sm, 32);
        sq += __shfl_xor(sq, 16);
        sq += __shfl_xor(sq, 32);
        if (q == 0) {
            unsafeAtomicAdd(&stats1[c], sm);
            unsafeAtomicAdd(&stats1[DD2 + c], sq);
        }
    }
}

// ---------------- persistent fp16 MFMA GEMM2, BN1+relu fused on A, atomic col stats ----------

template <int K, int M, int JW, int GX, bool FUSEA>
__global__ __launch_bounds__(256, 2) void mfma_gemm_persist(
    const unsigned short* __restrict__ A, const unsigned short* __restrict__ Bt,
    const float* __restrict__ bias, const float* __restrict__ astats,
    const float* __restrict__ ag, const float* __restrict__ ab,
    unsigned short* __restrict__ C, float* __restrict__ stats) {
    const int KS = K / 32;
    const int GR = (NN + 63) / 64;  // 782
    int wave = threadIdx.x >> 6;
    int lane = threadIdx.x & 63;
    int wr = wave >> 1, wc = wave & 1;
    int col0 = blockIdx.y * (JW * 32) + wc * (JW * 16);
    int lr = lane & 15;
    int q = lane >> 4;

    __shared__ _Float16 s_sh[FUSEA ? K : 1], t_sh[FUSEA ? K : 1];
    half8 sa[FUSEA ? KS : 1], ta[FUSEA ? KS : 1];
    if (FUSEA) {
        for (int c = threadIdx.x; c < K; c += 256) {
            float mean = astats[c] * (1.f / NN);
            float var = astats[K + c] * (1.f / NN) - mean * mean;
            float sc = ag[c] * rsqrtf(var + BN_EPS);
            s_sh[c] = (_Float16)sc;
            t_sh[c] = (_Float16)(ab[c] - mean * sc);
        }
        __syncthreads();
#pragma unroll
        for (int ks = 0; ks < KS; ks++) {
            sa[ks] = *(const half8*)(s_sh + ks * 32 + q * 8);
            ta[ks] = *(const half8*)(t_sh + ks * 32 + q * 8);
        }
    }

    half8 b[JW][KS];
#pragma unroll
    for (int j = 0; j < JW; j++) {
        const unsigned short* bp = Bt + (size_t)(col0 + j * 16 + lr) * K + q * 8;
#pragma unroll
        for (int ks = 0; ks < KS; ks++)
            b[j][ks] = __builtin_bit_cast(half8, *(const int4*)(bp + ks * 32));
    }

    float bi[JW];
#pragma unroll
    for (int j = 0; j < JW; j++) bi[j] = bias[col0 + j * 16 + lr];

    float s_acc[JW], sq_acc[JW];
#pragma unroll
    for (int j = 0; j < JW; j++) { s_acc[j] = 0.f; sq_acc[j] = 0.f; }

    for (int rb = blockIdx.x; rb < GR; rb += GX) {
        int row0 = rb * 64 + wr * 32;
        half8 a[2][KS];
#pragma unroll
        for (int i = 0; i < 2; i++) {
            const unsigned short* ap = A + (size_t)(row0 + i * 16 + lr) * K + q * 8;
#pragma unroll
            for (int ks = 0; ks < KS; ks++) {
                half8 av = __builtin_bit_cast(half8, *(const int4*)(ap + ks * 32));
                if (FUSEA) av = bnrelu8(av, sa[ks], ta[ks]);
                a[i][ks] = av;
            }
        }

        f32x4 acc[2][JW];
#pragma unroll
        for (int i = 0; i < 2; i++)
#pragma unroll
            for (int j = 0; j < JW; j++) acc[i][j] = (f32x4){0.f, 0.f, 0.f, 0.f};

#pragma unroll
        for (int ks = 0; ks < KS; ks++)
#pragma unroll
            for (int i = 0; i < 2; i++)
#pragma unroll
                for (int j = 0; j < JW; j++)
                    acc[i][j] = __builtin_amdgcn_mfma_f32_16x16x32_f16(a[i][ks], b[j][ks], acc[i][j], 0, 0, 0);

#pragma unroll
        for (int j = 0; j < JW; j++) {
            int c = col0 + j * 16 + lr;
#pragma unroll
            for (int i = 0; i < 2; i++) {
#pragma unroll
                for (int r = 0; r < 4; r++) {
                    int row = row0 + i * 16 + q * 4 + r;
                    if (row < NN) {
                        float v = acc[i][j][r] + bi[j];
                        C[(size_t)row * M + c] = f2h_bits(v);
                        s_acc[j] += v;
                        sq_acc[j] += v * v;
                    }
                }
            }
        }
    }

#pragma unroll
    for (int j = 0; j < JW; j++) {
        int c = col0 + j * 16 + lr;
        float s = s_acc[j], sq = sq_acc[j];
        s += __shfl_xor(s, 16);
        s += __shfl_xor(s, 32);
        sq += __shfl_xor(sq, 16);
        sq += __shfl_xor(sq, 32);
        if (q == 0) {
            unsafeAtomicAdd(&stats[c], s);
            unsafeAtomicAdd(&stats[M + c], sq);
        }
    }
}

// ---------------- BN apply 2, last layer only: z2 fp16 -> d_out fp32 (no relu) ---------------

__global__ void bnapply2_last_kernel(const unsigned short* __restrict__ z,
                                     const float* __restrict__ stats, const float* __restrict__ g,
                                     const float* __restrict__ bb, float* __restrict__ fout) {
    __shared__ float s_sh[DD], t_sh[DD];
    if (threadIdx.x < DD) {
        int c = threadIdx.x;
        float mean = stats[c] * (1.f / NN);
        float var = stats[DD + c] * (1.f / NN) - mean * mean;
        float sc = g[c] * rsqrtf(var + BN_EPS);
        s_sh[c] = sc;
        t_sh[c] = bb[c] - mean * sc;
    }
    __syncthreads();
    int i = (blockIdx.x * 256 + threadIdx.x) * 4;
    int c = i & 127;
    uint2 in = *(const uint2*)(z + i);
    float4 out;
    out.x = h2f((unsigned short)(in.x & 0xffff)) * s_sh[c] + t_sh[c];
    out.y = h2f((unsigned short)(in.x >> 16)) * s_sh[c + 1] + t_sh[c + 1];
    out.z = h2f((unsigned short)(in.y & 0xffff)) * s_sh[c + 2] + t_sh[c + 2];
    out.w = h2f((unsigned short)(in.y >> 16)) * s_sh[c + 3] + t_sh[c + 3];
    *(float4*)(fout + i) = out;
}

// ---------------- launch ----------------

extern "C" void kernel_launch(void* const* d_in, const int* in_sizes, int n_in,
                              void* d_out, int out_size, void* d_ws, size_t ws_size,
                              hipStream_t stream) {
    const int* x = (const int*)d_in[0];
    const int* edge_index = (const int*)d_in[1];
    const int* edge_attr = (const int*)d_in[2];
    const float* edge_weight = (const float*)d_in[3];
    const float* atom_emb = (const float*)d_in[4];
    const float* bond_emb = (const float*)d_in[5];
    const float* W1 = (const float*)d_in[6];
    const float* b1 = (const float*)d_in[7];
    const float* bn1_g = (const float*)d_in[8];
    const float* bn1_b = (const float*)d_in[9];
    const float* W2 = (const float*)d_in[10];
    const float* b2 = (const float*)d_in[11];
    const float* eps_p = (const float*)d_in[12];
    const float* bn_g = (const float*)d_in[13];
    const float* bn_b = (const float*)d_in[14];
    const int* srcv = edge_index;
    const int* dstv = edge_index + EE;

    char* p = (char*)d_ws;
    auto alloc = [&](size_t bytes) {
        void* r = (void*)p;
        p += (bytes + 255) & ~(size_t)255;
        return r;
    };
    unsigned short* h = (unsigned short*)alloc((size_t)NN * DD * 2);    // layer-0 node state
    unsigned short* z1 = (unsigned short*)alloc((size_t)NN * DD2 * 2);  // gemm1 out fp16 (pre-BN)
    unsigned short* z2 = (unsigned short*)alloc((size_t)NN * DD * 2);   // gemm2 out fp16 (pre-BN)
    uint2* edata = (uint2*)alloc((size_t)EE * 8);
    int* counts = (int*)alloc((size_t)NN * 4);
    int* row_ptr = (int*)alloc((size_t)(NN + 1) * 4);
    int* blksum = (int*)alloc(256 * 4);
    int* order = (int*)alloc((size_t)NN * 4);
    int* dbin = (int*)alloc(128 * 4);
    unsigned short* W1t = (unsigned short*)alloc((size_t)LL * DD * DD2 * 2);
    unsigned short* W2t = (unsigned short*)alloc((size_t)LL * DD * DD2 * 2);
    unsigned short* bsum = (unsigned short*)alloc((size_t)LL * 512 * DD * 2);
    float* statsAll = (float*)alloc((size_t)(LL * 512 + LL * 256) * 4);
    float* stats1Base = statsAll;
    float* stats2Base = statsAll + LL * 512;

    // --- one-time prep ---
    hipMemsetAsync(counts, 0, (size_t)NN * 4, stream);
    hipMemsetAsync(statsAll, 0, (size_t)(LL * 512 + LL * 256) * 4, stream);
    hipMemsetAsync(dbin, 0, 128 * 4, stream);
    hist_kernel<<<(EE + 255) / 256, 256, 0, stream>>>(dstv, counts);
    int nblk = (NN + 255) / 256;
    scan1_kernel<<<nblk, 256, 0, stream>>>(counts, row_ptr, blksum);
    scan2_kernel<<<1, 256, 0, stream>>>(blksum, nblk);
    scan3_kernel<<<nblk, 256, 0, stream>>>(row_ptr, blksum);
    hipMemsetAsync(counts, 0, (size_t)NN * 4, stream);
    scatter_kernel<<<(EE + 255) / 256, 256, 0, stream>>>(dstv, srcv, edge_attr, edge_weight,
                                                         row_ptr, counts, edata);
    deg_hist_kernel<<<nblk, 256, 0, stream>>>(row_ptr, dbin);
    deg_scan_kernel<<<1, 128, 0, stream>>>(dbin);
    deg_scatter_kernel<<<nblk, 256, 0, stream>>>(row_ptr, dbin, order);
    prep_tables_kernel<<<(2 * LL * DD * DD2 + LL * 512 * DD + 255) / 256, 256, 0, stream>>>(
        W1, W2, bond_emb, W1t, W2t, bsum);
    init_h_kernel<<<NN / 8, 256, 0, stream>>>(x, atom_emb, h);

    for (int l = 0; l < LL; l++) {
        float* stats1 = stats1Base + l * 512;
        float* stats2 = stats2Base + l * 256;
        const unsigned short* bsum_l = bsum + (size_t)l * 512 * DD;
        const unsigned short* W1tl = W1t + (size_t)l * DD * DD2;

        if (l == 0) {
            agg_mlp1_kernel<false><<<NN / 16, 256, 0, stream>>>(
                h, nullptr, nullptr, nullptr, row_ptr, edata, bsum_l, eps_p + l, order, W1tl,
                b1 + l * DD2, z1, stats1);
        } else {
            agg_mlp1_kernel<true><<<NN / 16, 256, 0, stream>>>(
                z2, stats2Base + (l - 1) * 256, bn_g + (l - 1) * DD, bn_b + (l - 1) * DD, row_ptr,
                edata, bsum_l, eps_p + l, order, W1tl, b1 + l * DD2, z1, stats1);
        }

        // GEMM2: K=256, M=128, JW=2, 512 blocks, BN1+relu fused on A
        mfma_gemm_persist<DD2, DD, 2, 256, true><<<dim3(256, 2), 256, 0, stream>>>(
            z1, W2t + (size_t)l * DD * DD2, b2 + l * DD, stats1, bn1_g + l * DD2, bn1_b + l * DD2,
            z2, stats2);
    }

    bnapply2_last_kernel<<<NN * DD / 1024, 256, 0, stream>>>(
        z2, stats2Base + (LL - 1) * 256, bn_g + (LL - 1) * DD, bn_b + (LL - 1) * DD,
        (float*)d_out);
}

// Round 10
// 832.868 us; speedup vs baseline: 1.3721x; 1.3721x over previous
//
#include <hip/hip_runtime.h>

#define NN 50000
#define EE 600000
#define DD 128
#define DD2 256
#define LL 5
#define BN_EPS 1e-5f

typedef __attribute__((ext_vector_type(8))) _Float16 half8;
typedef __attribute__((ext_vector_type(4))) float f32x4;

__device__ inline unsigned short f2h_bits(float f) {
    _Float16 h = (_Float16)f;  // RTNE
    return __builtin_bit_cast(unsigned short, h);
}
__device__ inline float h2f(unsigned short u) {
    return (float)__builtin_bit_cast(_Float16, u);
}
__device__ inline half8 bnrelu8(half8 v, half8 s, half8 t) {
    half8 r = v * s + t;
#pragma unroll
    for (int k = 0; k < 8; k++) r[k] = (r[k] > (_Float16)0) ? r[k] : (_Float16)0;
    return r;
}

// ---------------- CSR build ----------------

__global__ void hist_kernel(const int* __restrict__ dst, int* __restrict__ counts) {
    int e = blockIdx.x * blockDim.x + threadIdx.x;
    if (e < EE) atomicAdd(&counts[dst[e]], 1);
}

__global__ void scan1_kernel(const int* __restrict__ counts, int* __restrict__ row_ptr,
                             int* __restrict__ blksum) {
    __shared__ int tmp[256];
    int i = blockIdx.x * 256 + threadIdx.x;
    int v = (i < NN) ? counts[i] : 0;
    tmp[threadIdx.x] = v;
    __syncthreads();
    for (int off = 1; off < 256; off <<= 1) {
        int x = 0;
        if (threadIdx.x >= off) x = tmp[threadIdx.x - off];
        __syncthreads();
        if (threadIdx.x >= off) tmp[threadIdx.x] += x;
        __syncthreads();
    }
    if (i < NN) row_ptr[i] = tmp[threadIdx.x] - v;
    if (threadIdx.x == 255) blksum[blockIdx.x] = tmp[255];
}

__global__ void scan2_kernel(int* __restrict__ blksum, int nblocks) {
    __shared__ int tmp[256];
    int v = (threadIdx.x < nblocks) ? blksum[threadIdx.x] : 0;
    tmp[threadIdx.x] = v;
    __syncthreads();
    for (int off = 1; off < 256; off <<= 1) {
        int x = 0;
        if (threadIdx.x >= off) x = tmp[threadIdx.x - off];
        __syncthreads();
        if (threadIdx.x >= off) tmp[threadIdx.x] += x;
        __syncthreads();
    }
    blksum[threadIdx.x] = tmp[threadIdx.x] - v;
}

__global__ void scan3_kernel(int* __restrict__ row_ptr, const int* __restrict__ blksum) {
    int i = blockIdx.x * 256 + threadIdx.x;
    if (i < NN) row_ptr[i] += blksum[blockIdx.x];
    if (i == 0) row_ptr[NN] = EE;
}

// scatter + pack edge data: edata[p] = {src, cid | w_fp16<<16}
__global__ void scatter_kernel(const int* __restrict__ dst, const int* __restrict__ src,
                               const int* __restrict__ edge_attr, const float* __restrict__ ew,
                               const int* __restrict__ row_ptr, int* __restrict__ cursor,
                               uint2* __restrict__ edata) {
    int e = blockIdx.x * blockDim.x + threadIdx.x;
    if (e < EE) {
        int d = dst[e];
        int p = row_ptr[d] + atomicAdd(&cursor[d], 1);
        int cid = edge_attr[3 * e + 0] + 8 * edge_attr[3 * e + 1] + 64 * edge_attr[3 * e + 2];
        uint2 v;
        v.x = (unsigned)src[e];
        v.y = (unsigned)cid | ((unsigned)f2h_bits(ew[e]) << 16);
        edata[p] = v;
    }
}

// ---------------- table prep: W1t, W2t (fp16, [M][K]) + combined bond table (fp16) ------------

__global__ void prep_tables_kernel(const float* __restrict__ W1, const float* __restrict__ W2,
                                   const float* __restrict__ bond_emb,
                                   unsigned short* __restrict__ W1t,
                                   unsigned short* __restrict__ W2t,
                                   unsigned short* __restrict__ bsum) {
    const int NW = LL * DD * DD2;  // 163840
    int idx = blockIdx.x * 256 + threadIdx.x;
    if (idx < NW) {
        int l = idx / (DD * DD2);
        int rem = idx - l * DD * DD2;
        int k = rem / DD2, m = rem - k * DD2;  // W1: [L][128][256]
        W1t[(size_t)l * DD * DD2 + (size_t)m * DD + k] = f2h_bits(W1[idx]);
    } else if (idx < 2 * NW) {
        int j = idx - NW;
        int l = j / (DD * DD2);
        int rem = j - l * DD * DD2;
        int k = rem / DD, m = rem - k * DD;  // W2: [L][256][128]
        W2t[(size_t)l * DD * DD2 + (size_t)m * DD2 + k] = f2h_bits(W2[j]);
    } else if (idx < 2 * NW + LL * 512 * DD) {
        int j = idx - 2 * NW;
        int l = j >> 16;  // 512*128
        int rem = j & 65535;
        int cid = rem >> 7, d = rem & 127;
        int a0 = cid & 7, a1 = (cid >> 3) & 7, a2 = cid >> 6;
        const float* base = bond_emb + (size_t)l * 3 * 8 * DD;
        bsum[j] = f2h_bits(base[a0 * DD + d] + base[(8 + a1) * DD + d] + base[(16 + a2) * DD + d]);
    }
}

// ---------------- node init (fp16 h0) ----------------

__global__ void init_h_kernel(const int* __restrict__ x, const float* __restrict__ atom_emb,
                              unsigned short* __restrict__ h) {
    int n = blockIdx.x * 8 + (threadIdx.x >> 5);
    int lane = threadIdx.x & 31;
    float a0 = 0.f, a1 = 0.f, a2 = 0.f, a3 = 0.f;
#pragma unroll
    for (int f = 0; f < 9; f++) {
        int idx = x[n * 9 + f];
        const float4 v = *(const float4*)(atom_emb + ((size_t)(f * 64 + idx) * DD) + lane * 4);
        a0 += v.x; a1 += v.y; a2 += v.z; a3 += v.w;
    }
    ushort4 o;
    o.x = f2h_bits(a0); o.y = f2h_bits(a1); o.z = f2h_bits(a2); o.w = f2h_bits(a3);
    *(ushort4*)(h + (size_t)n * DD + lane * 4) = o;
}

// ---------------- FUSED: edge aggregate (+BN2+relu of prev layer) + GEMM1 + stats1 -----------
// Block = 16 consecutive nodes. Phase 1: gather 16x128 A-tile into LDS (16 lanes/node, uint4).
// Phase 2: A-tile @ W1t (K=128 -> M=256) via MFMA, +bias, write z1 (coalesced), atomic stats.

template <bool FUSE>
__global__ __launch_bounds__(256, 4) void agg_mlp1_kernel(
    const unsigned short* __restrict__ hsrc, const float* __restrict__ stats,
    const float* __restrict__ g, const float* __restrict__ bb,
    const int* __restrict__ row_ptr, const uint2* __restrict__ edata,
    const unsigned short* __restrict__ bsum_l, const float* __restrict__ eps_ptr,
    const unsigned short* __restrict__ W1t, const float* __restrict__ bias1,
    unsigned short* __restrict__ z1, float* __restrict__ stats1) {
    __shared__ _Float16 As[16 * DD];
    int tid = threadIdx.x;
    int lane16 = tid & 15;
    int s = tid >> 4;  // 0..15 sub-node
    int c0 = lane16 * 8;
    int n = blockIdx.x * 16 + s;

    float bs[8], bt[8];
    if (FUSE) {
#pragma unroll
        for (int k = 0; k < 8; k++) {
            int c = c0 + k;
            float mean = stats[c] * (1.f / NN);
            float var = stats[DD + c] * (1.f / NN) - mean * mean;
            float sc = g[c] * rsqrtf(var + BN_EPS);
            bs[k] = sc;
            bt[k] = bb[c] - mean * sc;
        }
    }

    float acc[8] = {0.f, 0.f, 0.f, 0.f, 0.f, 0.f, 0.f, 0.f};

    auto accum = [&](uint2 ed, uint4 hz, uint4 bz) {
        float w = h2f((unsigned short)(ed.y >> 16));
        unsigned int hw[4] = {hz.x, hz.y, hz.z, hz.w};
        unsigned int bw[4] = {bz.x, bz.y, bz.z, bz.w};
#pragma unroll
        for (int k = 0; k < 4; k++) {
            float hv0 = h2f((unsigned short)(hw[k] & 0xffff));
            float hv1 = h2f((unsigned short)(hw[k] >> 16));
            if (FUSE) {
                hv0 = fmaxf(hv0 * bs[2 * k] + bt[2 * k], 0.f);
                hv1 = fmaxf(hv1 * bs[2 * k + 1] + bt[2 * k + 1], 0.f);
            }
            float m0 = fmaxf(hv0 + h2f((unsigned short)(bw[k] & 0xffff)), 0.f);
            float m1 = fmaxf(hv1 + h2f((unsigned short)(bw[k] >> 16)), 0.f);
            acc[2 * k] += m0 * w;
            acc[2 * k + 1] += m1 * w;
        }
    };

    int beg = row_ptr[n], end = row_ptr[n + 1];
    int i = beg;
    for (; i + 4 <= end; i += 4) {
        uint2 e0 = edata[i], e1 = edata[i + 1], e2 = edata[i + 2], e3 = edata[i + 3];
        uint4 h0 = *(const uint4*)(hsrc + (size_t)e0.x * DD + c0);
        uint4 b0 = *(const uint4*)(bsum_l + (size_t)(e0.y & 0xffff) * DD + c0);
        uint4 h1 = *(const uint4*)(hsrc + (size_t)e1.x * DD + c0);
        uint4 b1 = *(const uint4*)(bsum_l + (size_t)(e1.y & 0xffff) * DD + c0);
        uint4 h2 = *(const uint4*)(hsrc + (size_t)e2.x * DD + c0);
        uint4 b2 = *(const uint4*)(bsum_l + (size_t)(e2.y & 0xffff) * DD + c0);
        uint4 h3 = *(const uint4*)(hsrc + (size_t)e3.x * DD + c0);
        uint4 b3 = *(const uint4*)(bsum_l + (size_t)(e3.y & 0xffff) * DD + c0);
        accum(e0, h0, b0);
        accum(e1, h1, b1);
        accum(e2, h2, b2);
        accum(e3, h3, b3);
    }
    for (; i < end; i++) {
        uint2 e0 = edata[i];
        uint4 h0 = *(const uint4*)(hsrc + (size_t)e0.x * DD + c0);
        uint4 b0 = *(const uint4*)(bsum_l + (size_t)(e0.y & 0xffff) * DD + c0);
        accum(e0, h0, b0);
    }

    // self term + pack to LDS
    {
        float eps1 = 1.f + eps_ptr[0];
        uint4 hz = *(const uint4*)(hsrc + (size_t)n * DD + c0);
        unsigned int hw[4] = {hz.x, hz.y, hz.z, hz.w};
        uint4 packed;
        unsigned int* pp = (unsigned int*)&packed;
#pragma unroll
        for (int k = 0; k < 4; k++) {
            float hv0 = h2f((unsigned short)(hw[k] & 0xffff));
            float hv1 = h2f((unsigned short)(hw[k] >> 16));
            if (FUSE) {
                hv0 = fmaxf(hv0 * bs[2 * k] + bt[2 * k], 0.f);
                hv1 = fmaxf(hv1 * bs[2 * k + 1] + bt[2 * k + 1], 0.f);
            }
            float v0 = eps1 * hv0 + acc[2 * k];
            float v1 = eps1 * hv1 + acc[2 * k + 1];
            pp[k] = (unsigned int)f2h_bits(v0) | ((unsigned int)f2h_bits(v1) << 16);
        }
        *(uint4*)(As + s * DD + c0) = packed;
    }
    __syncthreads();

    // ---- phase 2: 16x128 @ 128x256 ----
    int wave = tid >> 6;
    int lane = tid & 63;
    int lr = lane & 15;
    int q = lane >> 4;
    int colbase = wave * 64;

    half8 bfr[4][4];  // [j][ks]
#pragma unroll
    for (int j = 0; j < 4; j++) {
        const unsigned short* bp = W1t + (size_t)(colbase + j * 16 + lr) * DD + q * 8;
#pragma unroll
        for (int ks = 0; ks < 4; ks++)
            bfr[j][ks] = __builtin_bit_cast(half8, *(const int4*)(bp + ks * 32));
    }
    half8 afr[4];
#pragma unroll
    for (int ks = 0; ks < 4; ks++)
        afr[ks] = *(const half8*)(As + lr * DD + ks * 32 + q * 8);

    f32x4 acc4[4];
#pragma unroll
    for (int j = 0; j < 4; j++) acc4[j] = (f32x4){0.f, 0.f, 0.f, 0.f};
#pragma unroll
    for (int ks = 0; ks < 4; ks++)
#pragma unroll
        for (int j = 0; j < 4; j++)
            acc4[j] = __builtin_amdgcn_mfma_f32_16x16x32_f16(afr[ks], bfr[j][ks], acc4[j], 0, 0, 0);

#pragma unroll
    for (int j = 0; j < 4; j++) {
        int c = colbase + j * 16 + lr;
        float bi = bias1[c];
        float sm = 0.f, sq = 0.f;
#pragma unroll
        for (int r = 0; r < 4; r++) {
            int row = blockIdx.x * 16 + q * 4 + r;
            float v = acc4[j][r] + bi;
            z1[(size_t)row * DD2 + c] = f2h_bits(v);
            sm += v;
            sq += v * v;
        }
        sm += __shfl_xor(sm, 16);
        sm += __shfl_xor(sm, 32);
        sq += __shfl_xor(sq, 16);
        sq += __shfl_xor(sq, 32);
        if (q == 0) {
            unsafeAtomicAdd(&stats1[c], sm);
            unsafeAtomicAdd(&stats1[DD2 + c], sq);
        }
    }
}

// ---------------- persistent fp16 MFMA GEMM2, BN1+relu fused on A, atomic col stats ----------

template <int K, int M, int JW, int GX, bool FUSEA>
__global__ __launch_bounds__(256, 2) void mfma_gemm_persist(
    const unsigned short* __restrict__ A, const unsigned short* __restrict__ Bt,
    const float* __restrict__ bias, const float* __restrict__ astats,
    const float* __restrict__ ag, const float* __restrict__ ab,
    unsigned short* __restrict__ C, float* __restrict__ stats) {
    const int KS = K / 32;
    const int GR = (NN + 63) / 64;  // 782
    int wave = threadIdx.x >> 6;
    int lane = threadIdx.x & 63;
    int wr = wave >> 1, wc = wave & 1;
    int col0 = blockIdx.y * (JW * 32) + wc * (JW * 16);
    int lr = lane & 15;
    int q = lane >> 4;

    __shared__ _Float16 s_sh[FUSEA ? K : 1], t_sh[FUSEA ? K : 1];
    half8 sa[FUSEA ? KS : 1], ta[FUSEA ? KS : 1];
    if (FUSEA) {
        for (int c = threadIdx.x; c < K; c += 256) {
            float mean = astats[c] * (1.f / NN);
            float var = astats[K + c] * (1.f / NN) - mean * mean;
            float sc = ag[c] * rsqrtf(var + BN_EPS);
            s_sh[c] = (_Float16)sc;
            t_sh[c] = (_Float16)(ab[c] - mean * sc);
        }
        __syncthreads();
#pragma unroll
        for (int ks = 0; ks < KS; ks++) {
            sa[ks] = *(const half8*)(s_sh + ks * 32 + q * 8);
            ta[ks] = *(const half8*)(t_sh + ks * 32 + q * 8);
        }
    }

    half8 b[JW][KS];
#pragma unroll
    for (int j = 0; j < JW; j++) {
        const unsigned short* bp = Bt + (size_t)(col0 + j * 16 + lr) * K + q * 8;
#pragma unroll
        for (int ks = 0; ks < KS; ks++)
            b[j][ks] = __builtin_bit_cast(half8, *(const int4*)(bp + ks * 32));
    }

    float bi[JW];
#pragma unroll
    for (int j = 0; j < JW; j++) bi[j] = bias[col0 + j * 16 + lr];

    float s_acc[JW], sq_acc[JW];
#pragma unroll
    for (int j = 0; j < JW; j++) { s_acc[j] = 0.f; sq_acc[j] = 0.f; }

    for (int rb = blockIdx.x; rb < GR; rb += GX) {
        int row0 = rb * 64 + wr * 32;
        half8 a[2][KS];
#pragma unroll
        for (int i = 0; i < 2; i++) {
            const unsigned short* ap = A + (size_t)(row0 + i * 16 + lr) * K + q * 8;
#pragma unroll
            for (int ks = 0; ks < KS; ks++) {
                half8 av = __builtin_bit_cast(half8, *(const int4*)(ap + ks * 32));
                if (FUSEA) av = bnrelu8(av, sa[ks], ta[ks]);
                a[i][ks] = av;
            }
        }

        f32x4 acc[2][JW];
#pragma unroll
        for (int i = 0; i < 2; i++)
#pragma unroll
            for (int j = 0; j < JW; j++) acc[i][j] = (f32x4){0.f, 0.f, 0.f, 0.f};

#pragma unroll
        for (int ks = 0; ks < KS; ks++)
#pragma unroll
            for (int i = 0; i < 2; i++)
#pragma unroll
                for (int j = 0; j < JW; j++)
                    acc[i][j] = __builtin_amdgcn_mfma_f32_16x16x32_f16(a[i][ks], b[j][ks], acc[i][j], 0, 0, 0);

#pragma unroll
        for (int j = 0; j < JW; j++) {
            int c = col0 + j * 16 + lr;
#pragma unroll
            for (int i = 0; i < 2; i++) {
#pragma unroll
                for (int r = 0; r < 4; r++) {
                    int row = row0 + i * 16 + q * 4 + r;
                    if (row < NN) {
                        float v = acc[i][j][r] + bi[j];
                        C[(size_t)row * M + c] = f2h_bits(v);
                        s_acc[j] += v;
                        sq_acc[j] += v * v;
                    }
                }
            }
        }
    }

#pragma unroll
    for (int j = 0; j < JW; j++) {
        int c = col0 + j * 16 + lr;
        float s = s_acc[j], sq = sq_acc[j];
        s += __shfl_xor(s, 16);
        s += __shfl_xor(s, 32);
        sq += __shfl_xor(sq, 16);
        sq += __shfl_xor(sq, 32);
        if (q == 0) {
            unsafeAtomicAdd(&stats[c], s);
            unsafeAtomicAdd(&stats[M + c], sq);
        }
    }
}

// ---------------- BN apply 2, last layer only: z2 fp16 -> d_out fp32 (no relu) ---------------

__global__ void bnapply2_last_kernel(const unsigned short* __restrict__ z,
                                     const float* __restrict__ stats, const float* __restrict__ g,
                                     const float* __restrict__ bb, float* __restrict__ fout) {
    __shared__ float s_sh[DD], t_sh[DD];
    if (threadIdx.x < DD) {
        int c = threadIdx.x;
        float mean = stats[c] * (1.f / NN);
        float var = stats[DD + c] * (1.f / NN) - mean * mean;
        float sc = g[c] * rsqrtf(var + BN_EPS);
        s_sh[c] = sc;
        t_sh[c] = bb[c] - mean * sc;
    }
    __syncthreads();
    int i = (blockIdx.x * 256 + threadIdx.x) * 4;
    int c = i & 127;
    uint2 in = *(const uint2*)(z + i);
    float4 out;
    out.x = h2f((unsigned short)(in.x & 0xffff)) * s_sh[c] + t_sh[c];
    out.y = h2f((unsigned short)(in.x >> 16)) * s_sh[c + 1] + t_sh[c + 1];
    out.z = h2f((unsigned short)(in.y & 0xffff)) * s_sh[c + 2] + t_sh[c + 2];
    out.w = h2f((unsigned short)(in.y >> 16)) * s_sh[c + 3] + t_sh[c + 3];
    *(float4*)(fout + i) = out;
}

// ---------------- launch ----------------

extern "C" void kernel_launch(void* const* d_in, const int* in_sizes, int n_in,
                              void* d_out, int out_size, void* d_ws, size_t ws_size,
                              hipStream_t stream) {
    const int* x = (const int*)d_in[0];
    const int* edge_index = (const int*)d_in[1];
    const int* edge_attr = (const int*)d_in[2];
    const float* edge_weight = (const float*)d_in[3];
    const float* atom_emb = (const float*)d_in[4];
    const float* bond_emb = (const float*)d_in[5];
    const float* W1 = (const float*)d_in[6];
    const float* b1 = (const float*)d_in[7];
    const float* bn1_g = (const float*)d_in[8];
    const float* bn1_b = (const float*)d_in[9];
    const float* W2 = (const float*)d_in[10];
    const float* b2 = (const float*)d_in[11];
    const float* eps_p = (const float*)d_in[12];
    const float* bn_g = (const float*)d_in[13];
    const float* bn_b = (const float*)d_in[14];
    const int* srcv = edge_index;
    const int* dstv = edge_index + EE;

    char* p = (char*)d_ws;
    auto alloc = [&](size_t bytes) {
        void* r = (void*)p;
        p += (bytes + 255) & ~(size_t)255;
        return r;
    };
    unsigned short* h = (unsigned short*)alloc((size_t)NN * DD * 2);    // layer-0 node state
    unsigned short* z1 = (unsigned short*)alloc((size_t)NN * DD2 * 2);  // gemm1 out fp16 (pre-BN)
    unsigned short* z2 = (unsigned short*)alloc((size_t)NN * DD * 2);   // gemm2 out fp16 (pre-BN)
    uint2* edata = (uint2*)alloc((size_t)EE * 8);
    int* counts = (int*)alloc((size_t)NN * 4);
    int* row_ptr = (int*)alloc((size_t)(NN + 1) * 4);
    int* blksum = (int*)alloc(256 * 4);
    unsigned short* W1t = (unsigned short*)alloc((size_t)LL * DD * DD2 * 2);
    unsigned short* W2t = (unsigned short*)alloc((size_t)LL * DD * DD2 * 2);
    unsigned short* bsum = (unsigned short*)alloc((size_t)LL * 512 * DD * 2);
    float* statsAll = (float*)alloc((size_t)(LL * 512 + LL * 256) * 4);
    float* stats1Base = statsAll;
    float* stats2Base = statsAll + LL * 512;

    // --- one-time prep ---
    hipMemsetAsync(counts, 0, (size_t)NN * 4, stream);
    hipMemsetAsync(statsAll, 0, (size_t)(LL * 512 + LL * 256) * 4, stream);
    hist_kernel<<<(EE + 255) / 256, 256, 0, stream>>>(dstv, counts);
    int nblk = (NN + 255) / 256;
    scan1_kernel<<<nblk, 256, 0, stream>>>(counts, row_ptr, blksum);
    scan2_kernel<<<1, 256, 0, stream>>>(blksum, nblk);
    scan3_kernel<<<nblk, 256, 0, stream>>>(row_ptr, blksum);
    hipMemsetAsync(counts, 0, (size_t)NN * 4, stream);
    scatter_kernel<<<(EE + 255) / 256, 256, 0, stream>>>(dstv, srcv, edge_attr, edge_weight,
                                                         row_ptr, counts, edata);
    prep_tables_kernel<<<(2 * LL * DD * DD2 + LL * 512 * DD + 255) / 256, 256, 0, stream>>>(
        W1, W2, bond_emb, W1t, W2t, bsum);
    init_h_kernel<<<NN / 8, 256, 0, stream>>>(x, atom_emb, h);

    for (int l = 0; l < LL; l++) {
        float* stats1 = stats1Base + l * 512;
        float* stats2 = stats2Base + l * 256;
        const unsigned short* bsum_l = bsum + (size_t)l * 512 * DD;
        const unsigned short* W1tl = W1t + (size_t)l * DD * DD2;

        if (l == 0) {
            agg_mlp1_kernel<false><<<(NN + 15) / 16, 256, 0, stream>>>(
                h, nullptr, nullptr, nullptr, row_ptr, edata, bsum_l, eps_p + l, W1tl,
                b1 + l * DD2, z1, stats1);
        } else {
            agg_mlp1_kernel<true><<<(NN + 15) / 16, 256, 0, stream>>>(
                z2, stats2Base + (l - 1) * 256, bn_g + (l - 1) * DD, bn_b + (l - 1) * DD, row_ptr,
                edata, bsum_l, eps_p + l, W1tl, b1 + l * DD2, z1, stats1);
        }

        // GEMM2: K=256, M=128, JW=2, 512 blocks, BN1+relu fused on A
        mfma_gemm_persist<DD2, DD, 2, 256, true><<<dim3(256, 2), 256, 0, stream>>>(
            z1, W2t + (size_t)l * DD * DD2, b2 + l * DD, stats1, bn1_g + l * DD2, bn1_b + l * DD2,
            z2, stats2);
    }

    bnapply2_last_kernel<<<NN * DD / 1024, 256, 0, stream>>>(
        z2, stats2Base + (LL - 1) * 256, bn_g + (LL - 1) * DD, bn_b + (LL - 1) * DD,
        (float*)d_out);
}

// Round 11
// 757.668 us; speedup vs baseline: 1.5083x; 1.0993x over previous
//
#include <hip/hip_runtime.h>

#define NN 50000
#define EE 600000
#define DD 128
#define DD2 256
#define LL 5
#define BN_EPS 1e-5f

typedef __attribute__((ext_vector_type(8))) _Float16 half8;
typedef __attribute__((ext_vector_type(4))) float f32x4;

__device__ inline unsigned short f2h_bits(float f) {
    _Float16 h = (_Float16)f;  // RTNE
    return __builtin_bit_cast(unsigned short, h);
}
__device__ inline float h2f(unsigned short u) {
    return (float)__builtin_bit_cast(_Float16, u);
}
__device__ inline half8 bnrelu8(half8 v, half8 s, half8 t) {
    half8 r = v * s + t;
#pragma unroll
    for (int k = 0; k < 8; k++) r[k] = (r[k] > (_Float16)0) ? r[k] : (_Float16)0;
    return r;
}

// ---------------- CSR build ----------------

__global__ void hist_kernel(const int* __restrict__ dst, int* __restrict__ counts) {
    int e = blockIdx.x * blockDim.x + threadIdx.x;
    if (e < EE) atomicAdd(&counts[dst[e]], 1);
}

__global__ void scan1_kernel(const int* __restrict__ counts, int* __restrict__ row_ptr,
                             int* __restrict__ blksum) {
    __shared__ int tmp[256];
    int i = blockIdx.x * 256 + threadIdx.x;
    int v = (i < NN) ? counts[i] : 0;
    tmp[threadIdx.x] = v;
    __syncthreads();
    for (int off = 1; off < 256; off <<= 1) {
        int x = 0;
        if (threadIdx.x >= off) x = tmp[threadIdx.x - off];
        __syncthreads();
        if (threadIdx.x >= off) tmp[threadIdx.x] += x;
        __syncthreads();
    }
    if (i < NN) row_ptr[i] = tmp[threadIdx.x] - v;
    if (threadIdx.x == 255) blksum[blockIdx.x] = tmp[255];
}

__global__ void scan2_kernel(int* __restrict__ blksum, int nblocks) {
    __shared__ int tmp[256];
    int v = (threadIdx.x < nblocks) ? blksum[threadIdx.x] : 0;
    tmp[threadIdx.x] = v;
    __syncthreads();
    for (int off = 1; off < 256; off <<= 1) {
        int x = 0;
        if (threadIdx.x >= off) x = tmp[threadIdx.x - off];
        __syncthreads();
        if (threadIdx.x >= off) tmp[threadIdx.x] += x;
        __syncthreads();
    }
    blksum[threadIdx.x] = tmp[threadIdx.x] - v;
}

__global__ void scan3_kernel(int* __restrict__ row_ptr, const int* __restrict__ blksum) {
    int i = blockIdx.x * 256 + threadIdx.x;
    if (i < NN) row_ptr[i] += blksum[blockIdx.x];
    if (i == 0) row_ptr[NN] = EE;
}

// scatter + pack edge data: edata[p] = {src, cid | w_fp16<<16}
__global__ void scatter_kernel(const int* __restrict__ dst, const int* __restrict__ src,
                               const int* __restrict__ edge_attr, const float* __restrict__ ew,
                               const int* __restrict__ row_ptr, int* __restrict__ cursor,
                               uint2* __restrict__ edata) {
    int e = blockIdx.x * blockDim.x + threadIdx.x;
    if (e < EE) {
        int d = dst[e];
        int p = row_ptr[d] + atomicAdd(&cursor[d], 1);
        int cid = edge_attr[3 * e + 0] + 8 * edge_attr[3 * e + 1] + 64 * edge_attr[3 * e + 2];
        uint2 v;
        v.x = (unsigned)src[e];
        v.y = (unsigned)cid | ((unsigned)f2h_bits(ew[e]) << 16);
        edata[p] = v;
    }
}

// ---------------- table prep: W1t, W2t (fp16, [M][K]) + combined bond table (fp16) ------------

__global__ void prep_tables_kernel(const float* __restrict__ W1, const float* __restrict__ W2,
                                   const float* __restrict__ bond_emb,
                                   unsigned short* __restrict__ W1t,
                                   unsigned short* __restrict__ W2t,
                                   unsigned short* __restrict__ bsum) {
    const int NW = LL * DD * DD2;  // 163840
    int idx = blockIdx.x * 256 + threadIdx.x;
    if (idx < NW) {
        int l = idx / (DD * DD2);
        int rem = idx - l * DD * DD2;
        int k = rem / DD2, m = rem - k * DD2;  // W1: [L][128][256]
        W1t[(size_t)l * DD * DD2 + (size_t)m * DD + k] = f2h_bits(W1[idx]);
    } else if (idx < 2 * NW) {
        int j = idx - NW;
        int l = j / (DD * DD2);
        int rem = j - l * DD * DD2;
        int k = rem / DD, m = rem - k * DD;  // W2: [L][256][128]
        W2t[(size_t)l * DD * DD2 + (size_t)m * DD2 + k] = f2h_bits(W2[j]);
    } else if (idx < 2 * NW + LL * 512 * DD) {
        int j = idx - 2 * NW;
        int l = j >> 16;  // 512*128
        int rem = j & 65535;
        int cid = rem >> 7, d = rem & 127;
        int a0 = cid & 7, a1 = (cid >> 3) & 7, a2 = cid >> 6;
        const float* base = bond_emb + (size_t)l * 3 * 8 * DD;
        bsum[j] = f2h_bits(base[a0 * DD + d] + base[(8 + a1) * DD + d] + base[(16 + a2) * DD + d]);
    }
}

// ---------------- node init (fp16 h0) ----------------

__global__ void init_h_kernel(const int* __restrict__ x, const float* __restrict__ atom_emb,
                              unsigned short* __restrict__ h) {
    int n = blockIdx.x * 8 + (threadIdx.x >> 5);
    int lane = threadIdx.x & 31;
    float a0 = 0.f, a1 = 0.f, a2 = 0.f, a3 = 0.f;
#pragma unroll
    for (int f = 0; f < 9; f++) {
        int idx = x[n * 9 + f];
        const float4 v = *(const float4*)(atom_emb + ((size_t)(f * 64 + idx) * DD) + lane * 4);
        a0 += v.x; a1 += v.y; a2 += v.z; a3 += v.w;
    }
    ushort4 o;
    o.x = f2h_bits(a0); o.y = f2h_bits(a1); o.z = f2h_bits(a2); o.w = f2h_bits(a3);
    *(ushort4*)(h + (size_t)n * DD + lane * 4) = o;
}

// ---------------- edge aggregate → A fp16, optional fused BN2+relu on gathered rows ----------

template <bool FUSE>
__global__ __launch_bounds__(256, 6) void agg_kernel(
    const unsigned short* __restrict__ hsrc, const float* __restrict__ stats,
    const float* __restrict__ g, const float* __restrict__ bb, const int* __restrict__ row_ptr,
    const uint2* __restrict__ edata, const unsigned short* __restrict__ bsum_l,
    const float* __restrict__ eps_ptr, unsigned short* __restrict__ Aout) {
    int n = blockIdx.x * 8 + (threadIdx.x >> 5);
    int lane = threadIdx.x & 31;
    int c0 = lane * 4;

    float bs[4] = {1.f, 1.f, 1.f, 1.f}, bt[4] = {0.f, 0.f, 0.f, 0.f};
    if (FUSE) {
        float4 sm = *(const float4*)(stats + c0);
        float4 sq = *(const float4*)(stats + DD + c0);
        float4 gg = *(const float4*)(g + c0);
        float4 bv = *(const float4*)(bb + c0);
        float mv[4] = {sm.x, sm.y, sm.z, sm.w};
        float qv[4] = {sq.x, sq.y, sq.z, sq.w};
        float gv[4] = {gg.x, gg.y, gg.z, gg.w};
        float bbv[4] = {bv.x, bv.y, bv.z, bv.w};
#pragma unroll
        for (int k = 0; k < 4; k++) {
            float mean = mv[k] * (1.f / NN);
            float var = qv[k] * (1.f / NN) - mean * mean;
            bs[k] = gv[k] * rsqrtf(var + BN_EPS);
            bt[k] = bbv[k] - mean * bs[k];
        }
    }

    auto accum = [&](uint2 ed, uint2 hz, uint2 bz, float* acc) {
        float w = h2f((unsigned short)(ed.y >> 16));
        unsigned int hw[2] = {hz.x, hz.y}, bw[2] = {bz.x, bz.y};
#pragma unroll
        for (int k = 0; k < 2; k++) {
            float hv0 = h2f((unsigned short)(hw[k] & 0xffff));
            float hv1 = h2f((unsigned short)(hw[k] >> 16));
            if (FUSE) {
                hv0 = fmaxf(hv0 * bs[2 * k] + bt[2 * k], 0.f);
                hv1 = fmaxf(hv1 * bs[2 * k + 1] + bt[2 * k + 1], 0.f);
            }
            float m0 = fmaxf(hv0 + h2f((unsigned short)(bw[k] & 0xffff)), 0.f);
            float m1 = fmaxf(hv1 + h2f((unsigned short)(bw[k] >> 16)), 0.f);
            acc[2 * k] += m0 * w;
            acc[2 * k + 1] += m1 * w;
        }
    };

    int beg = row_ptr[n], end = row_ptr[n + 1];
    float acc[4] = {0.f, 0.f, 0.f, 0.f};
    int i = beg;
    for (; i + 4 <= end; i += 4) {
        uint2 e0 = edata[i], e1 = edata[i + 1], e2 = edata[i + 2], e3 = edata[i + 3];
        uint2 h0 = *(const uint2*)(hsrc + (size_t)e0.x * DD + c0);
        uint2 b0 = *(const uint2*)(bsum_l + (size_t)(e0.y & 0xffff) * DD + c0);
        uint2 h1 = *(const uint2*)(hsrc + (size_t)e1.x * DD + c0);
        uint2 b1 = *(const uint2*)(bsum_l + (size_t)(e1.y & 0xffff) * DD + c0);
        uint2 h2 = *(const uint2*)(hsrc + (size_t)e2.x * DD + c0);
        uint2 b2 = *(const uint2*)(bsum_l + (size_t)(e2.y & 0xffff) * DD + c0);
        uint2 h3 = *(const uint2*)(hsrc + (size_t)e3.x * DD + c0);
        uint2 b3 = *(const uint2*)(bsum_l + (size_t)(e3.y & 0xffff) * DD + c0);
        accum(e0, h0, b0, acc);
        accum(e1, h1, b1, acc);
        accum(e2, h2, b2, acc);
        accum(e3, h3, b3, acc);
    }
    for (; i < end; i++) {
        uint2 e0 = edata[i];
        uint2 h0 = *(const uint2*)(hsrc + (size_t)e0.x * DD + c0);
        uint2 b0 = *(const uint2*)(bsum_l + (size_t)(e0.y & 0xffff) * DD + c0);
        accum(e0, h0, b0, acc);
    }

    float eps1 = 1.f + eps_ptr[0];
    uint2 hz = *(const uint2*)(hsrc + (size_t)n * DD + c0);
    unsigned int hw[2] = {hz.x, hz.y};
    float self[4];
#pragma unroll
    for (int k = 0; k < 2; k++) {
        float hv0 = h2f((unsigned short)(hw[k] & 0xffff));
        float hv1 = h2f((unsigned short)(hw[k] >> 16));
        if (FUSE) {
            hv0 = fmaxf(hv0 * bs[2 * k] + bt[2 * k], 0.f);
            hv1 = fmaxf(hv1 * bs[2 * k + 1] + bt[2 * k + 1], 0.f);
        }
        self[2 * k] = hv0;
        self[2 * k + 1] = hv1;
    }
    ushort4 o;
    o.x = f2h_bits(eps1 * self[0] + acc[0]);
    o.y = f2h_bits(eps1 * self[1] + acc[1]);
    o.z = f2h_bits(eps1 * self[2] + acc[2]);
    o.w = f2h_bits(eps1 * self[3] + acc[3]);
    *(ushort4*)(Aout + (size_t)n * DD + c0) = o;
}

// ---------------- persistent fp16 MFMA GEMM, reg-resident B, atomic col stats ----------------
// C(NN x M) = act(A)(NN x K) @ Bt^T + bias, fp16 out.
// FUSEA: A-fragments get relu(a*s+t) with s/t from astats/ag/ab (BN1 fused into GEMM2).

template <int K, int M, int JW, int GX, bool FUSEA>
__global__ __launch_bounds__(256, 2) void mfma_gemm_persist(
    const unsigned short* __restrict__ A, const unsigned short* __restrict__ Bt,
    const float* __restrict__ bias, const float* __restrict__ astats,
    const float* __restrict__ ag, const float* __restrict__ ab,
    unsigned short* __restrict__ C, float* __restrict__ stats) {
    const int KS = K / 32;
    const int GR = (NN + 63) / 64;  // 782
    int wave = threadIdx.x >> 6;
    int lane = threadIdx.x & 63;
    int wr = wave >> 1, wc = wave & 1;
    int col0 = blockIdx.y * (JW * 32) + wc * (JW * 16);
    int lr = lane & 15;
    int q = lane >> 4;

    __shared__ _Float16 s_sh[FUSEA ? K : 1], t_sh[FUSEA ? K : 1];
    half8 sa[FUSEA ? KS : 1], ta[FUSEA ? KS : 1];
    if (FUSEA) {
        for (int c = threadIdx.x; c < K; c += 256) {
            float mean = astats[c] * (1.f / NN);
            float var = astats[K + c] * (1.f / NN) - mean * mean;
            float sc = ag[c] * rsqrtf(var + BN_EPS);
            s_sh[c] = (_Float16)sc;
            t_sh[c] = (_Float16)(ab[c] - mean * sc);
        }
        __syncthreads();
#pragma unroll
        for (int ks = 0; ks < KS; ks++) {
            sa[ks] = *(const half8*)(s_sh + ks * 32 + q * 8);
            ta[ks] = *(const half8*)(t_sh + ks * 32 + q * 8);
        }
    }

    half8 b[JW][KS];
#pragma unroll
    for (int j = 0; j < JW; j++) {
        const unsigned short* bp = Bt + (size_t)(col0 + j * 16 + lr) * K + q * 8;
#pragma unroll
        for (int ks = 0; ks < KS; ks++)
            b[j][ks] = __builtin_bit_cast(half8, *(const int4*)(bp + ks * 32));
    }

    float bi[JW];
#pragma unroll
    for (int j = 0; j < JW; j++) bi[j] = bias[col0 + j * 16 + lr];

    float s_acc[JW], sq_acc[JW];
#pragma unroll
    for (int j = 0; j < JW; j++) { s_acc[j] = 0.f; sq_acc[j] = 0.f; }

    for (int rb = blockIdx.x; rb < GR; rb += GX) {
        int row0 = rb * 64 + wr * 32;
        half8 a[2][KS];
#pragma unroll
        for (int i = 0; i < 2; i++) {
            const unsigned short* ap = A + (size_t)(row0 + i * 16 + lr) * K + q * 8;
#pragma unroll
            for (int ks = 0; ks < KS; ks++) {
                half8 av = __builtin_bit_cast(half8, *(const int4*)(ap + ks * 32));
                if (FUSEA) av = bnrelu8(av, sa[ks], ta[ks]);
                a[i][ks] = av;
            }
        }

        f32x4 acc[2][JW];
#pragma unroll
        for (int i = 0; i < 2; i++)
#pragma unroll
            for (int j = 0; j < JW; j++) acc[i][j] = (f32x4){0.f, 0.f, 0.f, 0.f};

#pragma unroll
        for (int ks = 0; ks < KS; ks++)
#pragma unroll
            for (int i = 0; i < 2; i++)
#pragma unroll
                for (int j = 0; j < JW; j++)
                    acc[i][j] = __builtin_amdgcn_mfma_f32_16x16x32_f16(a[i][ks], b[j][ks], acc[i][j], 0, 0, 0);

#pragma unroll
        for (int j = 0; j < JW; j++) {
            int c = col0 + j * 16 + lr;
#pragma unroll
            for (int i = 0; i < 2; i++) {
#pragma unroll
                for (int r = 0; r < 4; r++) {
                    int row = row0 + i * 16 + q * 4 + r;
                    if (row < NN) {
                        float v = acc[i][j][r] + bi[j];
                        C[(size_t)row * M + c] = f2h_bits(v);
                        s_acc[j] += v;
                        sq_acc[j] += v * v;
                    }
                }
            }
        }
    }

#pragma unroll
    for (int j = 0; j < JW; j++) {
        int c = col0 + j * 16 + lr;
        float s = s_acc[j], sq = sq_acc[j];
        s += __shfl_xor(s, 16);
        s += __shfl_xor(s, 32);
        sq += __shfl_xor(sq, 16);
        sq += __shfl_xor(sq, 32);
        if (q == 0) {
            unsafeAtomicAdd(&stats[c], s);
            unsafeAtomicAdd(&stats[M + c], sq);
        }
    }
}

// ---------------- BN apply 2, last layer only: z2 fp16 -> d_out fp32 (no relu) ---------------

__global__ void bnapply2_last_kernel(const unsigned short* __restrict__ z,
                                     const float* __restrict__ stats, const float* __restrict__ g,
                                     const float* __restrict__ bb, float* __restrict__ fout) {
    __shared__ float s_sh[DD], t_sh[DD];
    if (threadIdx.x < DD) {
        int c = threadIdx.x;
        float mean = stats[c] * (1.f / NN);
        float var = stats[DD + c] * (1.f / NN) - mean * mean;
        float sc = g[c] * rsqrtf(var + BN_EPS);
        s_sh[c] = sc;
        t_sh[c] = bb[c] - mean * sc;
    }
    __syncthreads();
    int i = (blockIdx.x * 256 + threadIdx.x) * 4;
    int c = i & 127;
    uint2 in = *(const uint2*)(z + i);
    float4 out;
    out.x = h2f((unsigned short)(in.x & 0xffff)) * s_sh[c] + t_sh[c];
    out.y = h2f((unsigned short)(in.x >> 16)) * s_sh[c + 1] + t_sh[c + 1];
    out.z = h2f((unsigned short)(in.y & 0xffff)) * s_sh[c + 2] + t_sh[c + 2];
    out.w = h2f((unsigned short)(in.y >> 16)) * s_sh[c + 3] + t_sh[c + 3];
    *(float4*)(fout + i) = out;
}

// ---------------- launch ----------------

extern "C" void kernel_launch(void* const* d_in, const int* in_sizes, int n_in,
                              void* d_out, int out_size, void* d_ws, size_t ws_size,
                              hipStream_t stream) {
    const int* x = (const int*)d_in[0];
    const int* edge_index = (const int*)d_in[1];
    const int* edge_attr = (const int*)d_in[2];
    const float* edge_weight = (const float*)d_in[3];
    const float* atom_emb = (const float*)d_in[4];
    const float* bond_emb = (const float*)d_in[5];
    const float* W1 = (const float*)d_in[6];
    const float* b1 = (const float*)d_in[7];
    const float* bn1_g = (const float*)d_in[8];
    const float* bn1_b = (const float*)d_in[9];
    const float* W2 = (const float*)d_in[10];
    const float* b2 = (const float*)d_in[11];
    const float* eps_p = (const float*)d_in[12];
    const float* bn_g = (const float*)d_in[13];
    const float* bn_b = (const float*)d_in[14];
    const int* srcv = edge_index;
    const int* dstv = edge_index + EE;

    char* p = (char*)d_ws;
    auto alloc = [&](size_t bytes) {
        void* r = (void*)p;
        p += (bytes + 255) & ~(size_t)255;
        return r;
    };
    unsigned short* h = (unsigned short*)alloc((size_t)NN * DD * 2);    // layer-0 node state
    unsigned short* z1 = (unsigned short*)alloc((size_t)NN * DD2 * 2);  // gemm1 out fp16 (pre-BN)
    unsigned short* z2 = (unsigned short*)alloc((size_t)NN * DD * 2);   // gemm2 out fp16 (pre-BN)
    unsigned short* A1h = (unsigned short*)alloc((size_t)NN * DD * 2);  // agg out fp16
    uint2* edata = (uint2*)alloc((size_t)EE * 8);
    int* counts = (int*)alloc((size_t)NN * 4);
    int* row_ptr = (int*)alloc((size_t)(NN + 1) * 4);
    int* blksum = (int*)alloc(256 * 4);
    unsigned short* W1t = (unsigned short*)alloc((size_t)LL * DD * DD2 * 2);
    unsigned short* W2t = (unsigned short*)alloc((size_t)LL * DD * DD2 * 2);
    unsigned short* bsum = (unsigned short*)alloc((size_t)LL * 512 * DD * 2);
    float* statsAll = (float*)alloc((size_t)(LL * 512 + LL * 256) * 4);
    float* stats1Base = statsAll;
    float* stats2Base = statsAll + LL * 512;

    // --- one-time prep ---
    hipMemsetAsync(counts, 0, (size_t)NN * 4, stream);
    hipMemsetAsync(statsAll, 0, (size_t)(LL * 512 + LL * 256) * 4, stream);
    hist_kernel<<<(EE + 255) / 256, 256, 0, stream>>>(dstv, counts);
    int nblk = (NN + 255) / 256;
    scan1_kernel<<<nblk, 256, 0, stream>>>(counts, row_ptr, blksum);
    scan2_kernel<<<1, 256, 0, stream>>>(blksum, nblk);
    scan3_kernel<<<nblk, 256, 0, stream>>>(row_ptr, blksum);
    hipMemsetAsync(counts, 0, (size_t)NN * 4, stream);
    scatter_kernel<<<(EE + 255) / 256, 256, 0, stream>>>(dstv, srcv, edge_attr, edge_weight,
                                                         row_ptr, counts, edata);
    prep_tables_kernel<<<(2 * LL * DD * DD2 + LL * 512 * DD + 255) / 256, 256, 0, stream>>>(
        W1, W2, bond_emb, W1t, W2t, bsum);
    init_h_kernel<<<NN / 8, 256, 0, stream>>>(x, atom_emb, h);

    for (int l = 0; l < LL; l++) {
        float* stats1 = stats1Base + l * 512;
        float* stats2 = stats2Base + l * 256;
        const unsigned short* bsum_l = bsum + (size_t)l * 512 * DD;

        if (l == 0) {
            agg_kernel<false><<<NN / 8, 256, 0, stream>>>(h, nullptr, nullptr, nullptr, row_ptr,
                                                          edata, bsum_l, eps_p + l, A1h);
        } else {
            agg_kernel<true><<<NN / 8, 256, 0, stream>>>(
                z2, stats2Base + (l - 1) * 256, bn_g + (l - 1) * DD, bn_b + (l - 1) * DD, row_ptr,
                edata, bsum_l, eps_p + l, A1h);
        }

        // GEMM1: K=128, M=256, JW=4, GX=256 -> 512 blocks (2/CU)
        mfma_gemm_persist<DD, DD2, 4, 256, false><<<dim3(256, 2), 256, 0, stream>>>(
            A1h, W1t + (size_t)l * DD * DD2, b1 + l * DD2, nullptr, nullptr, nullptr, z1, stats1);

        // GEMM2: K=256, M=128, JW=2, GX=384 -> 768 blocks (3/CU at VGPR 96), BN1+relu fused on A
        mfma_gemm_persist<DD2, DD, 2, 384, true><<<dim3(384, 2), 256, 0, stream>>>(
            z1, W2t + (size_t)l * DD * DD2, b2 + l * DD, stats1, bn1_g + l * DD2, bn1_b + l * DD2,
            z2, stats2);
    }

    bnapply2_last_kernel<<<NN * DD / 1024, 256, 0, stream>>>(
        z2, stats2Base + (LL - 1) * 256, bn_g + (LL - 1) * DD, bn_b + (LL - 1) * DD,
        (float*)d_out);
}